// Round 2
// baseline (210.174 us; speedup 1.0000x reference)
//
#include <hip/hip_runtime.h>
#include <hip/hip_bf16.h>
#include <stdint.h>

#define B_ 4
#define S_ 1024
#define D_ 1024
#define E_ 8
#define DE_ 128
#define SCALE_ 0.03125f   // 1/sqrt(1024)

typedef __attribute__((ext_vector_type(8))) short short8;
typedef __attribute__((ext_vector_type(4))) float f32x4;
typedef unsigned short ushort_t;
typedef unsigned int uint32;

__device__ __forceinline__ ushort_t f2bf(float f) {
    uint32 u = __float_as_uint(f);
    uint32 r = u + 0x7fffu + ((u >> 16) & 1u);   // round-to-nearest-even
    return (ushort_t)(r >> 16);
}
__device__ __forceinline__ float bf2f(ushort_t h) {
    return __uint_as_float(((uint32)h) << 16);
}

// ---------------------------------------------------------------------------
// Kernel 1: K fp32 [B][S][E*DE] -> bf16 [B][E][S][DE]
// ---------------------------------------------------------------------------
__global__ __launch_bounds__(256) void kprep_kernel(
        const float* __restrict__ K, ushort_t* __restrict__ Kb) {
    int i = blockIdx.x * 256 + threadIdx.x;          // 0 .. 1M-1 (float4 units)
    int dc = i & 31;                                  // DE/4 chunks
    int e  = (i >> 5) & 7;
    int s  = (i >> 8) & 1023;
    int b  = i >> 18;
    size_t in_off  = ((size_t)(b * 1024 + s) << 10) + ((size_t)e << 7) + ((size_t)dc << 2);
    size_t out_off = (((size_t)(b * 8 + e) * 1024 + s) << 7) + ((size_t)dc << 2);
    float4 k = *(const float4*)(K + in_off);
    *(ushort4*)(Kb + out_off) = make_ushort4(f2bf(k.x), f2bf(k.y), f2bf(k.z), f2bf(k.w));
}

// ---------------------------------------------------------------------------
// Kernel 2: V fp32 [B][S][E*DE] -> bf16 transposed Vt [B][E][DE][S]
// Block handles 128 s x 128 d of one (b,e) slice. LDS pitch 134:
// phase-2 column walk hits ~8 banks (acceptable, one-shot kernel).
// ---------------------------------------------------------------------------
__global__ __launch_bounds__(256) void vtrans_kernel(
        const float* __restrict__ V, ushort_t* __restrict__ Vt) {
    __shared__ ushort_t tile[128][134];
    const int tid = threadIdx.x;
    const int sc = blockIdx.x, e = blockIdx.y, b = blockIdx.z;
    const int s0 = sc * 128;

    const float* vsrc = V + ((size_t)(b * 1024 + s0) << 10) + (e << 7);
    #pragma unroll
    for (int j = 0; j < 16; ++j) {
        int idx = tid + j * 256, r = idx >> 5, c4 = idx & 31;
        float4 v = *(const float4*)(vsrc + ((size_t)r << 10) + (c4 << 2));
        ushort_t* p = &tile[r][c4 << 2];
        p[0] = f2bf(v.x); p[1] = f2bf(v.y); p[2] = f2bf(v.z); p[3] = f2bf(v.w);
    }
    __syncthreads();
    ushort_t* vdst = Vt + (((size_t)(b * 8 + e)) << 17) + s0;
    #pragma unroll
    for (int j = 0; j < 8; ++j) {
        int idx = tid + j * 256, d = idx >> 4, sg = idx & 15;
        union { uint4 q; ushort_t u[8]; } tmp;
        #pragma unroll
        for (int k = 0; k < 8; ++k) tmp.u[k] = tile[sg * 8 + k][d];
        *(uint4*)&vdst[((size_t)d << 10) + (sg << 3)] = tmp.q;
    }
}

// ---------------------------------------------------------------------------
// Kernel 3: attnHL[b][s][t] = pack_bf16_hi_lo( sum_e mask[e][b] *
//              softmax_t(QK/32) )   -- no max subtraction (scores ~N(0,0.35))
// Block = (stile16, b), 4 waves; wave w owns t in [256w, 256w+256).
// K staged per-wave (double-buffered, NO barriers in K loop).
// ---------------------------------------------------------------------------
__global__ __launch_bounds__(256, 1) void attn_pass1(
        const float* __restrict__ Q, const ushort_t* __restrict__ Kb,
        const int* __restrict__ em, uint32* __restrict__ attnHL) {

    __shared__ ushort_t qtile[16][136];
    __shared__ ushort_t ktile[4][2][64][136];   // per-wave double buffer
    __shared__ float    redbuf[4][16];

    const int tid  = threadIdx.x;
    const int w    = tid >> 6, lane = tid & 63;
    const int quad = lane >> 4, l16 = lane & 15;
    const int stile = blockIdx.x, b = blockIdx.y;
    const int s0 = stile * 16;

    const f32x4 zero4 = {0.f, 0.f, 0.f, 0.f};
    f32x4 aacc[16];
    #pragma unroll
    for (int i = 0; i < 16; ++i) aacc[i] = zero4;

    for (int e = 0; e < 8; ++e) {
        if (em[e * B_ + b] == 0) continue;     // uniform per block

        __syncthreads();                        // qtile/redbuf safe to rewrite
        {   // cooperative Q stage: 16 x 128 fp32 -> bf16
            const float* qsrc = Q + ((size_t)(b * 1024 + s0) << 10) + (e << 7);
            #pragma unroll
            for (int j = 0; j < 2; ++j) {
                int idx = tid + j * 256, r = idx >> 5, c4 = idx & 31;
                float4 q = *(const float4*)(qsrc + ((size_t)r << 10) + (c4 << 2));
                *(ushort4*)&qtile[r][c4 << 2] =
                    make_ushort4(f2bf(q.x), f2bf(q.y), f2bf(q.z), f2bf(q.w));
            }
        }
        __syncthreads();

        const ushort_t* ksrc0 = Kb + (((size_t)(b * 8 + e)) << 17) + ((size_t)w << 15);
        f32x4 sacc[16];
        #pragma unroll
        for (int i = 0; i < 16; ++i) sacc[i] = zero4;
        float rsum[4] = {0.f, 0.f, 0.f, 0.f};

        #pragma unroll
        for (int c = 0; c < 4; ++c) {
            const ushort_t* ksrc = ksrc0 + (c << 13);
            #pragma unroll
            for (int i2 = 0; i2 < 16; ++i2) {     // per-wave K stage, no barrier
                int i = i2 * 64 + lane, r = i >> 4, cc = (i & 15) << 3;
                *(uint4*)&ktile[w][c & 1][r][cc] = *(const uint4*)&ksrc[(r << 7) + cc];
            }
            #pragma unroll
            for (int kk = 0; kk < 128; kk += 32) {
                short8 afrag = *(const short8*)&qtile[l16][kk + quad * 8];
                #pragma unroll
                for (int n = 0; n < 4; ++n) {
                    short8 bfrag = *(const short8*)&ktile[w][c & 1][n * 16 + l16][kk + quad * 8];
                    sacc[c * 4 + n] = __builtin_amdgcn_mfma_f32_16x16x32_bf16(
                        afrag, bfrag, sacc[c * 4 + n], 0, 0, 0);
                }
            }
            #pragma unroll
            for (int n = 0; n < 4; ++n)
                #pragma unroll
                for (int r = 0; r < 4; ++r) {
                    float p = __expf(sacc[c * 4 + n][r] * SCALE_);
                    sacc[c * 4 + n][r] = p;
                    rsum[r] += p;
                }
        }

        // row sums: reduce over l16 lanes, then across 4 waves
        #pragma unroll
        for (int off = 1; off < 16; off <<= 1)
            #pragma unroll
            for (int r = 0; r < 4; ++r) rsum[r] += __shfl_xor(rsum[r], off, 64);
        if (l16 == 0) {
            #pragma unroll
            for (int r = 0; r < 4; ++r) redbuf[w][quad * 4 + r] = rsum[r];
        }
        __syncthreads();
        #pragma unroll
        for (int r = 0; r < 4; ++r) {
            float l = redbuf[0][quad * 4 + r] + redbuf[1][quad * 4 + r] +
                      redbuf[2][quad * 4 + r] + redbuf[3][quad * 4 + r];
            float rinv = 1.0f / l;
            #pragma unroll
            for (int i = 0; i < 16; ++i) aacc[i][r] += sacc[i][r] * rinv;
        }
    }

    // write packed hi/lo bf16 attn
    uint32* abase = attnHL + ((size_t)(b * 1024 + s0)) * 1024;
    #pragma unroll
    for (int i = 0; i < 16; ++i) {
        int t0 = w * 256 + ((i >> 2) << 6) + ((i & 3) << 4) + l16;
        #pragma unroll
        for (int r = 0; r < 4; ++r) {
            float v = aacc[i][r];
            ushort_t h = f2bf(v);
            ushort_t lo = f2bf(v - bf2f(h));
            abase[((size_t)(quad * 4 + r) << 10) + t0] = (((uint32)h) << 16) | lo;
        }
    }
}

// ---------------------------------------------------------------------------
// Kernel 4: out[b][s][e*128+d] = attn @ V_e for the 2 selected experts only.
// Grid (stile16, sel2, b4) = 512 blocks. t-chunks of 128. d_out pre-zeroed.
// ---------------------------------------------------------------------------
__global__ __launch_bounds__(256, 1) void attn_pass2(
        const ushort_t* __restrict__ Vt, const uint32* __restrict__ attnHL,
        const float* __restrict__ route, float* __restrict__ out) {

    const int stile = blockIdx.x;      // 0..63
    const int sel   = blockIdx.y;      // 0..1
    const int b     = blockIdx.z;      // 0..3
    const int s0  = stile * 16;
    const int tid = threadIdx.x;
    const int w = tid >> 6, lane = tid & 63, quad = lane >> 4, l16 = lane & 15;

    // top-2 (uniform per block; ties -> lower index, matches lax.top_k)
    const float* rp = route + b * 8;
    float v1 = rp[0]; int i1 = 0;
    #pragma unroll
    for (int i = 1; i < 8; ++i) { float v = rp[i]; if (v > v1) { v1 = v; i1 = i; } }
    float v2 = -1e30f; int i2 = 0;
    #pragma unroll
    for (int i = 0; i < 8; ++i) {
        if (i == i1) continue;
        float v = rp[i]; if (v > v2) { v2 = v; i2 = i; }
    }
    const int e = sel ? i2 : i1;

    __shared__ ushort_t aH[16][136];
    __shared__ ushort_t aL[16][136];
    __shared__ ushort_t vt[128][136];

    const uint32*   asrc = attnHL + ((size_t)(b * 1024 + s0)) * 1024;
    const ushort_t* vsrc = Vt + (((size_t)(b * 8 + e)) << 17);

    f32x4 oacc[2];
    oacc[0] = (f32x4){0.f, 0.f, 0.f, 0.f};
    oacc[1] = (f32x4){0.f, 0.f, 0.f, 0.f};

    for (int tc = 0; tc < 8; ++tc) {
        __syncthreads();
        #pragma unroll
        for (int j = 0; j < 2; ++j) {          // stage attn 16 x 128 (hi/lo split)
            int idx = tid + j * 256, r = idx >> 5, sg = idx & 31;
            uint4 u = *(const uint4*)&asrc[((size_t)r << 10) + (tc << 7) + (sg << 2)];
            *(ushort4*)&aH[r][sg << 2] = make_ushort4(
                (ushort_t)(u.x >> 16), (ushort_t)(u.y >> 16),
                (ushort_t)(u.z >> 16), (ushort_t)(u.w >> 16));
            *(ushort4*)&aL[r][sg << 2] = make_ushort4(
                (ushort_t)(u.x & 0xffff), (ushort_t)(u.y & 0xffff),
                (ushort_t)(u.z & 0xffff), (ushort_t)(u.w & 0xffff));
        }
        #pragma unroll
        for (int j = 0; j < 8; ++j) {          // stage Vt 128d x 128t
            int idx = tid + j * 256, d = idx >> 4, sg = idx & 15;
            *(uint4*)&vt[d][sg << 3] =
                *(const uint4*)&vsrc[((size_t)d << 10) + (tc << 7) + (sg << 3)];
        }
        __syncthreads();
        #pragma unroll
        for (int kk = 0; kk < 128; kk += 32) {
            short8 ah = *(const short8*)&aH[l16][kk + quad * 8];
            short8 al = *(const short8*)&aL[l16][kk + quad * 8];
            #pragma unroll
            for (int n = 0; n < 2; ++n) {
                int d0 = w * 32 + n * 16;
                short8 bf = *(const short8*)&vt[d0 + l16][kk + quad * 8];
                oacc[n] = __builtin_amdgcn_mfma_f32_16x16x32_bf16(ah, bf, oacc[n], 0, 0, 0);
                oacc[n] = __builtin_amdgcn_mfma_f32_16x16x32_bf16(al, bf, oacc[n], 0, 0, 0);
            }
        }
    }

    float* obase = out + ((size_t)(b * 1024 + s0)) * 1024 + e * 128;
    #pragma unroll
    for (int n = 0; n < 2; ++n) {
        int d0 = w * 32 + n * 16 + l16;
        #pragma unroll
        for (int r = 0; r < 4; ++r)
            obase[((size_t)(quad * 4 + r) << 10) + d0] = oacc[n][r];
    }
}

// ---------------------------------------------------------------------------
extern "C" void kernel_launch(void* const* d_in, const int* in_sizes, int n_in,
                              void* d_out, int out_size, void* d_ws, size_t ws_size,
                              hipStream_t stream) {
    const float* Q     = (const float*)d_in[0];
    const float* K     = (const float*)d_in[1];
    const float* V     = (const float*)d_in[2];
    const float* route = (const float*)d_in[3];
    const int*   em    = (const int*)d_in[4];
    float* out = (float*)d_out;

    const size_t NB = (size_t)B_ * E_ * S_ * DE_;   // 4.19M elements
    ushort_t* Kb = (ushort_t*)d_ws;
    ushort_t* Vt = Kb + NB;
    uint32* attnHL = (uint32*)(Vt + NB);            // [B][S][S] packed hi/lo bf16

    hipMemsetAsync(d_out, 0, (size_t)out_size * sizeof(float), stream);
    kprep_kernel<<<4096, 256, 0, stream>>>(K, Kb);
    dim3 gv(8, 8, 4);
    vtrans_kernel<<<gv, 256, 0, stream>>>(V, Vt);
    dim3 g1(64, 4);
    attn_pass1<<<g1, 256, 0, stream>>>(Q, Kb, em, attnHL);
    dim3 g2(64, 2, 4);
    attn_pass2<<<g2, 256, 0, stream>>>(Vt, attnHL, route, out);
}

// Round 3
// 184.734 us; speedup vs baseline: 1.1377x; 1.1377x over previous
//
#include <hip/hip_runtime.h>
#include <hip/hip_bf16.h>
#include <stdint.h>

#define B_ 4
#define S_ 1024
#define D_ 1024
#define E_ 8
#define DE_ 128
#define SCALE_ 0.03125f   // 1/sqrt(1024)

typedef __attribute__((ext_vector_type(8))) short short8;
typedef __attribute__((ext_vector_type(4))) float f32x4;
typedef unsigned short ushort_t;
typedef unsigned int uint32;

__device__ __forceinline__ ushort_t f2bf(float f) {
    uint32 u = __float_as_uint(f);
    uint32 r = u + 0x7fffu + ((u >> 16) & 1u);   // round-to-nearest-even
    return (ushort_t)(r >> 16);
}

// ---------------------------------------------------------------------------
// Kernel 1: K fp32 [B][S][E*DE] -> bf16 Kb [B][E][S][DE]
// ---------------------------------------------------------------------------
__global__ __launch_bounds__(256) void kprep_kernel(
        const float* __restrict__ K, ushort_t* __restrict__ Kb) {
    int i = blockIdx.x * 256 + threadIdx.x;          // float4 units
    int dc = i & 31;
    int e  = (i >> 5) & 7;
    int s  = (i >> 8) & 1023;
    int b  = i >> 18;
    size_t in_off  = ((size_t)(b * 1024 + s) << 10) + ((size_t)e << 7) + ((size_t)dc << 2);
    size_t out_off = (((size_t)(b * 8 + e) * 1024 + s) << 7) + ((size_t)dc << 2);
    float4 k = *(const float4*)(K + in_off);
    *(ushort4*)(Kb + out_off) = make_ushort4(f2bf(k.x), f2bf(k.y), f2bf(k.z), f2bf(k.w));
}

// ---------------------------------------------------------------------------
// Kernel 2: V fp32 [B][S][E*DE] -> bf16 transposed Vt [B][E][DE][S]
// ---------------------------------------------------------------------------
__global__ __launch_bounds__(256) void vtrans_kernel(
        const float* __restrict__ V, ushort_t* __restrict__ Vt) {
    __shared__ ushort_t tile[128][134];
    const int tid = threadIdx.x;
    const int sc = blockIdx.x, e = blockIdx.y, b = blockIdx.z;
    const int s0 = sc * 128;

    const float* vsrc = V + ((size_t)(b * 1024 + s0) << 10) + (e << 7);
    #pragma unroll
    for (int j = 0; j < 16; ++j) {
        int idx = tid + j * 256, r = idx >> 5, c4 = idx & 31;
        float4 v = *(const float4*)(vsrc + ((size_t)r << 10) + (c4 << 2));
        ushort_t* p = &tile[r][c4 << 2];
        p[0] = f2bf(v.x); p[1] = f2bf(v.y); p[2] = f2bf(v.z); p[3] = f2bf(v.w);
    }
    __syncthreads();
    ushort_t* vdst = Vt + (((size_t)(b * 8 + e)) << 17) + s0;
    #pragma unroll
    for (int j = 0; j < 8; ++j) {
        int idx = tid + j * 256, d = idx >> 4, sg = idx & 15;
        union { uint4 q; ushort_t u[8]; } tmp;
        #pragma unroll
        for (int k = 0; k < 8; ++k) tmp.u[k] = tile[sg * 8 + k][d];
        *(uint4*)&vdst[((size_t)d << 10) + (sg << 3)] = tmp.q;
    }
}

// ---------------------------------------------------------------------------
// Kernel 3: attnB[b][s][t] = bf16( sum_e mask[e][b] * softmax_t(QK/32) )
// Grid (stile16=64, b=4), block = 1024 threads = 16 waves.
// Wave w owns t-strip [64w, 64w+64). NO K/Q LDS: MFMA frags straight from
// global (16B/lane contiguous). One barrier per expert (row-sum reduce).
// ---------------------------------------------------------------------------
__global__ __launch_bounds__(1024) void attn_pass1(
        const float* __restrict__ Q, const ushort_t* __restrict__ Kb,
        const int* __restrict__ em, ushort_t* __restrict__ attnB) {

    __shared__ float redbuf[2][16][16];    // [parity][wave][row]

    const int tid  = threadIdx.x;
    const int w    = tid >> 6, lane = tid & 63;
    const int quad = lane >> 4, l16 = lane & 15;
    const int stile = blockIdx.x, b = blockIdx.y;
    const int s0 = stile * 16;
    const int T0 = w * 64;

    const f32x4 zero4 = {0.f, 0.f, 0.f, 0.f};
    f32x4 aacc[4];
    #pragma unroll
    for (int n = 0; n < 4; ++n) aacc[n] = zero4;

    int par = 0;
    for (int e = 0; e < 8; ++e) {
        if (em[e * B_ + b] == 0) continue;          // uniform per block

        // A-frags: Q rows (fp32 -> bf16 in-reg). A[m=l16][k=quad*8+j]
        short8 af[4];
        const float* qbase = Q + ((size_t)(b * 1024 + s0 + l16) << 10) + (e << 7) + quad * 8;
        #pragma unroll
        for (int kk = 0; kk < 4; ++kk) {
            float4 q0 = *(const float4*)(qbase + kk * 32);
            float4 q1 = *(const float4*)(qbase + kk * 32 + 4);
            union { short8 v; ushort_t u[8]; } a;
            a.u[0] = f2bf(q0.x); a.u[1] = f2bf(q0.y); a.u[2] = f2bf(q0.z); a.u[3] = f2bf(q0.w);
            a.u[4] = f2bf(q1.x); a.u[5] = f2bf(q1.y); a.u[6] = f2bf(q1.z); a.u[7] = f2bf(q1.w);
            af[kk] = a.v;
        }

        f32x4 sacc[4];
        #pragma unroll
        for (int n = 0; n < 4; ++n) sacc[n] = zero4;

        const ushort_t* kbase = Kb + (((size_t)(b * 8 + e)) << 17)
                                   + (((size_t)(T0 + l16)) << 7) + quad * 8;
        #pragma unroll
        for (int n = 0; n < 4; ++n) {
            #pragma unroll
            for (int kk = 0; kk < 4; ++kk) {
                short8 bf = *(const short8*)(kbase + (n << 11) + (kk << 5));
                sacc[n] = __builtin_amdgcn_mfma_f32_16x16x32_bf16(af[kk], bf, sacc[n], 0, 0, 0);
            }
        }

        // exp (no max-sub: scores ~N(0,0.35)) + partial row sums
        float rsum[4] = {0.f, 0.f, 0.f, 0.f};
        #pragma unroll
        for (int n = 0; n < 4; ++n)
            #pragma unroll
            for (int r = 0; r < 4; ++r) {
                float p = __expf(sacc[n][r] * SCALE_);
                sacc[n][r] = p;
                rsum[r] += p;
            }
        #pragma unroll
        for (int off = 1; off < 16; off <<= 1)
            #pragma unroll
            for (int r = 0; r < 4; ++r) rsum[r] += __shfl_xor(rsum[r], off, 64);
        if (l16 == 0) {
            #pragma unroll
            for (int r = 0; r < 4; ++r) redbuf[par][w][quad * 4 + r] = rsum[r];
        }
        __syncthreads();
        #pragma unroll
        for (int r = 0; r < 4; ++r) {
            float l = 0.f;
            #pragma unroll
            for (int ww = 0; ww < 16; ++ww) l += redbuf[par][ww][quad * 4 + r];
            float rinv = 1.0f / l;
            #pragma unroll
            for (int n = 0; n < 4; ++n) aacc[n][r] += sacc[n][r] * rinv;
        }
        par ^= 1;
    }

    // epilogue: attn tile -> bf16
    ushort_t* abase = attnB + (((size_t)(b * 1024 + s0)) << 10);
    #pragma unroll
    for (int n = 0; n < 4; ++n)
        #pragma unroll
        for (int r = 0; r < 4; ++r)
            abase[(((size_t)(quad * 4 + r)) << 10) + T0 + n * 16 + l16] = f2bf(aacc[n][r]);
}

// ---------------------------------------------------------------------------
// Kernel 4: out[b][s][e*128+d] = attn @ V_e for the 2 top-k experts.
// Grid (stile16=64, sel=2, b=4) = 512 blocks, 256 threads. Zero LDS:
// A-frags from attnB, B-frags from Vt, both 16B/lane global loads.
// Wave w owns d in [32w, 32w+32). d_out pre-zeroed by memset.
// ---------------------------------------------------------------------------
__global__ __launch_bounds__(256) void attn_pass2(
        const ushort_t* __restrict__ Vt, const ushort_t* __restrict__ attnB,
        const float* __restrict__ route, float* __restrict__ out) {

    const int stile = blockIdx.x;
    const int sel   = blockIdx.y;
    const int b     = blockIdx.z;
    const int s0  = stile * 16;
    const int tid = threadIdx.x;
    const int w = tid >> 6, lane = tid & 63, quad = lane >> 4, l16 = lane & 15;

    // top-2 (uniform; ties -> lower index, matches lax.top_k)
    const float* rp = route + b * 8;
    float v1 = rp[0]; int i1 = 0;
    #pragma unroll
    for (int i = 1; i < 8; ++i) { float v = rp[i]; if (v > v1) { v1 = v; i1 = i; } }
    float v2 = -1e30f; int i2 = 0;
    #pragma unroll
    for (int i = 0; i < 8; ++i) {
        if (i == i1) continue;
        float v = rp[i]; if (v > v2) { v2 = v; i2 = i; }
    }
    const int e = sel ? i2 : i1;

    const ushort_t* abase = attnB + (((size_t)(b * 1024 + s0 + l16)) << 10) + quad * 8;
    const ushort_t* vbase = Vt + (((size_t)(b * 8 + e)) << 17)
                               + (((size_t)(w * 32 + l16)) << 10) + quad * 8;

    f32x4 oacc[2];
    oacc[0] = (f32x4){0.f, 0.f, 0.f, 0.f};
    oacc[1] = (f32x4){0.f, 0.f, 0.f, 0.f};

    #pragma unroll 4
    for (int ts = 0; ts < 32; ++ts) {
        short8 A  = *(const short8*)(abase + (ts << 5));
        short8 B0 = *(const short8*)(vbase + (ts << 5));
        short8 B1 = *(const short8*)(vbase + (16 << 10) + (ts << 5));
        oacc[0] = __builtin_amdgcn_mfma_f32_16x16x32_bf16(A, B0, oacc[0], 0, 0, 0);
        oacc[1] = __builtin_amdgcn_mfma_f32_16x16x32_bf16(A, B1, oacc[1], 0, 0, 0);
    }

    float* obase = out + (((size_t)(b * 1024 + s0)) << 10) + e * 128;
    #pragma unroll
    for (int n = 0; n < 2; ++n)
        #pragma unroll
        for (int r = 0; r < 4; ++r)
            obase[(((size_t)(quad * 4 + r)) << 10) + w * 32 + n * 16 + l16] = oacc[n][r];
}

// ---------------------------------------------------------------------------
extern "C" void kernel_launch(void* const* d_in, const int* in_sizes, int n_in,
                              void* d_out, int out_size, void* d_ws, size_t ws_size,
                              hipStream_t stream) {
    const float* Q     = (const float*)d_in[0];
    const float* K     = (const float*)d_in[1];
    const float* V     = (const float*)d_in[2];
    const float* route = (const float*)d_in[3];
    const int*   em    = (const int*)d_in[4];
    float* out = (float*)d_out;

    const size_t NB = (size_t)B_ * E_ * S_ * DE_;   // 4.19M elements
    ushort_t* Kb = (ushort_t*)d_ws;
    ushort_t* Vt = Kb + NB;
    ushort_t* attnB = Vt + NB;                       // [B][S][S] bf16

    hipMemsetAsync(d_out, 0, (size_t)out_size * sizeof(float), stream);
    kprep_kernel<<<4096, 256, 0, stream>>>(K, Kb);
    dim3 gv(8, 8, 4);
    vtrans_kernel<<<gv, 256, 0, stream>>>(V, Vt);
    dim3 g1(64, 4);
    attn_pass1<<<g1, 1024, 0, stream>>>(Q, Kb, em, attnB);
    dim3 g2(64, 2, 4);
    attn_pass2<<<g2, 256, 0, stream>>>(Vt, attnB, route, out);
}